// Round 21
// baseline (254.865 us; speedup 1.0000x reference)
//
#include <hip/hip_runtime.h>
#include <hip/hip_bf16.h>

// ---------------------------------------------------------------------------
// Fused XCiT-style channel attention, one batch item per 512-thread block.
// B=2048, N=49 (7x7), DIM=384, HEADS=8, HD=48.
// R21: R20 exactly, minus the 13th (bias) MFMA k-step: biases are added in
// the epilogues instead (read-only acc preserved: xpose_n takes bias as a
// param; V store and P store add bias in f32). Saves ~48 MFMA + ~52 loads
// per wave (~7% of GEMM issue); also deletes the ones-column maintenance
// and the ks=12 row-48 overrun zeroing (ks<=11 stays inside X).
// ---------------------------------------------------------------------------

typedef __attribute__((ext_vector_type(8))) short short8;   // 8 x bf16 (4 VGPR)
typedef __attribute__((ext_vector_type(4))) short short4v;  // 4 x bf16 (8B)
typedef __attribute__((ext_vector_type(4))) float f32x4;    // MFMA acc

#define NPOS   49
#define DIMC   384
#define SCALE_QK 0.14433756729740643f   // 48^-0.5

// LDS map (bytes):
//  REGA = 0     : X bf16 [49][392] (38416) -> E bf16 [8][48] rows of 112B
//                 (43008) -> O/relu bf16 [49][392] (38416)
//  WOFF = 43008 : 288B f32 weight slot (64 w + 8 b; w1 then w2 time-shared)
//  REGB = 43296 : Vn bf16 [49][392] ([pos][ch], stride 784B)
#define REGA 0
#define WOFF 43008
#define REGB 43296
#define ESTR 112              // padded E row stride (bytes)
#define LDS_BYTES 81712

// per-gemm permuted-W block: 24 nt * 12 ks * 512 lane-slots
#define WBLK 147456

__device__ __forceinline__ unsigned short f2bf(float f) {
  __hip_bfloat16 h = __float2bfloat16(f);
  unsigned short u;
  __builtin_memcpy(&u, &h, 2);
  return u;
}
__device__ __forceinline__ float bf2f(unsigned short u) {
  union { unsigned u; float f; } v; v.u = ((unsigned)u) << 16;
  return v.f;
}

// ---- prologue: permute Wq,Wk,Wv,Wp (f32 [384][384]) into lane-ordered bf16
// fragment chunks (12 k-steps; biases now added in the main-kernel epilogues).
__global__ void wconv_kernel(const float* __restrict__ Wq, const float* __restrict__ Wk,
                             const float* __restrict__ Wv, const float* __restrict__ Wp,
                             unsigned short* __restrict__ dst) {
  int t = blockIdx.x * 256 + threadIdx.x;
  if (t >= 73728) return;            // 4 gemms * 24 nt * 12 ks * 64 lanes
  int l = t & 63;
  int u = t >> 6;
  int ks = u % 12; u /= 12;
  int nt = u % 24;
  int g  = u / 24;
  const float* W = (g == 0) ? Wq : (g == 1) ? Wk : (g == 2) ? Wv : Wp;
  int row = nt * 16 + (l & 15);
  const float* sp = W + row * 384 + ks * 32 + (l >> 4) * 8;
  short8 o8;
  #pragma unroll
  for (int j = 0; j < 8; ++j) o8[j] = (short)f2bf(sp[j]);
  *(short8*)(dst + (size_t)t * 8) = o8;
}

// 4-lane transpose of one n-tile D-fragment (bias added on the fly, acc
// stays read-only) into gram A/B fragments (pos = ks*32 + lhi*8 + j), plus
// per-channel inverse L2 norm.
__device__ __forceinline__ void xpose_n(const f32x4 (&acc)[4], float bias,
                                        int lhi, int llo,
                                        short8 (&fr)[2], float& sc) {
  float ss = 0.f;
  #pragma unroll
  for (int m = 0; m < 4; ++m)
    #pragma unroll
    for (int r = 0; r < 4; ++r) {
      int np = m * 16 + lhi * 4 + r;
      float v = acc[m][r] + bias;
      if (np < 49) ss += v * v;
    }
  ss += __shfl_xor(ss, 16, 64);
  ss += __shfl_xor(ss, 32, 64);
  sc = 1.f / fmaxf(sqrtf(ss), 1e-12f);
  const int src_lo = llo + ((lhi & 1) << 5);
  const int src_hi = src_lo + 16;
  #pragma unroll
  for (int m = 0; m < 4; ++m) {
    unsigned p0 = (unsigned)f2bf(acc[m][0] + bias) | ((unsigned)f2bf(acc[m][1] + bias) << 16);
    unsigned p1 = (unsigned)f2bf(acc[m][2] + bias) | ((unsigned)f2bf(acc[m][3] + bias) << 16);
    int lo0 = __shfl((int)p0, src_lo, 64);
    int lo1 = __shfl((int)p1, src_lo, 64);
    int hi0 = __shfl((int)p0, src_hi, 64);
    int hi1 = __shfl((int)p1, src_hi, 64);
    if ((lhi >> 1) == (m & 1)) {
      union { int i[4]; short8 s; } u;
      u.i[0] = lo0; u.i[1] = lo1; u.i[2] = hi0; u.i[3] = hi1;
      fr[m >> 1] = u.s;
    }
  }
  // zero pos>=49 in the ks=1 fragment (lhi==2: keep pos48; lhi==3: all pad)
  if (lhi == 2) {
    union { int i[4]; short8 s; } u; u.s = fr[1];
    u.i[0] &= 0xFFFF; u.i[1] = 0; u.i[2] = 0; u.i[3] = 0;
    fr[1] = u.s;
  } else if (lhi == 3) {
    short8 z = {0,0,0,0,0,0,0,0};
    fr[1] = z;
  }
}

// ---- main fused kernel -----------------------------------------------------
__global__ __launch_bounds__(512, 4) void attn_fused_kernel(
    const float* __restrict__ x,
    const float* __restrict__ bq, const float* __restrict__ bk,
    const float* __restrict__ bv, const float* __restrict__ bp,
    const float* __restrict__ Wvl, const float* __restrict__ bvl,
    const float* __restrict__ Wth1, const float* __restrict__ bth1,
    const float* __restrict__ Wth2, const float* __restrict__ bth2,
    const unsigned short* __restrict__ Wbf,
    float* __restrict__ out) {
  extern __shared__ char smem[];
  const int tid = threadIdx.x;
  const int l   = tid & 63;
  const int w   = tid >> 6;          // wave 0..7 == head h
  const int lhi = l >> 4;            // 0..3
  const int llo = l & 15;
  const int b   = blockIdx.x;

  const float* xb = x + (size_t)b * (NPOS * DIMC);
  const unsigned short* Wq_p = Wbf;
  const unsigned short* Wk_p = Wbf + WBLK;
  const unsigned short* Wv_p = Wbf + 2 * WBLK;
  const unsigned short* Wp_p = Wbf + 3 * WBLK;

  // ---- phase 0: stage x_b -> X bf16 [49][392] --------------------------------
  for (int idx = tid; idx < 49 * 48; idx += 512) {
    int row = idx / 48, c8 = idx % 48;
    const float4 v0 = *(const float4*)(xb + row * 384 + c8 * 8);
    const float4 v1 = *(const float4*)(xb + row * 384 + c8 * 8 + 4);
    short8 s;
    s[0] = (short)f2bf(v0.x); s[1] = (short)f2bf(v0.y);
    s[2] = (short)f2bf(v0.z); s[3] = (short)f2bf(v0.w);
    s[4] = (short)f2bf(v1.x); s[5] = (short)f2bf(v1.y);
    s[6] = (short)f2bf(v1.z); s[7] = (short)f2bf(v1.w);
    *(short8*)(smem + REGA + row * 784 + c8 * 16) = s;
  }
  __syncthreads();   // b1

  short8 qfv[3][2];
  float  qscv[3], kscv[3];
  f32x4 g[3][3] = {};                // gram acc, filled during the K pass

#define FENCE asm volatile("" ::: "memory")
  // 2-deep B-prefetch GEMM body (12 k-steps); MFMA cluster setprio-wrapped.
#define GEMM_N_PF2(WPTR, NIDX, ACC)                                            \
  {                                                                            \
    short8 bp0 = *(const short8*)(WPTR + (((w * 3 + NIDX) * 12 + 0) << 9) + (l << 3)); \
    short8 bp1 = *(const short8*)(WPTR + (((w * 3 + NIDX) * 12 + 1) << 9) + (l << 3)); \
    _Pragma("unroll")                                                          \
    for (int ks = 0; ks < 12; ++ks) {                                          \
      short8 bc = bp0; bp0 = bp1;                                              \
      if (ks < 10)                                                             \
        bp1 = *(const short8*)(WPTR + (((w * 3 + NIDX) * 12 + ks + 2) << 9) + (l << 3)); \
      short8 a[4];                                                             \
      _Pragma("unroll")                                                        \
      for (int m = 0; m < 4; ++m) {                                            \
        int row = m * 16 + llo; row = (row > 48) ? 48 : row;                   \
        a[m] = *(const short8*)(smem + REGA + row * 784 + ks * 64 + lhi * 16); \
      }                                                                        \
      __builtin_amdgcn_s_setprio(1);                                           \
      _Pragma("unroll")                                                        \
      for (int m = 0; m < 4; ++m)                                              \
        ACC[m] = __builtin_amdgcn_mfma_f32_16x16x32_bf16(a[m], bc, ACC[m], 0, 0, 0); \
      __builtin_amdgcn_s_setprio(0);                                           \
    }                                                                          \
  }

  // ---- V pass (per n-tile; biased V -> REGB [pos][ch], bias in epilogue) ----
  #pragma unroll
  for (int n = 0; n < 3; ++n) {
    f32x4 aV[4] = {};
    GEMM_N_PF2(Wv_p, n, aV);
    const int o = (w * 3 + n) * 16 + llo;
    const float bias = bv[o];
    #pragma unroll
    for (int m = 0; m < 4; ++m)
      #pragma unroll
      for (int r = 0; r < 4; ++r) {
        int np = m * 16 + lhi * 4 + r;
        if (np < 49)
          *(unsigned short*)(smem + REGB + np * 784 + o * 2) = f2bf(aV[m][r] + bias);
      }
    FENCE;
  }

  // ---- Q pass -> raw qf + inv norms (bias via xpose param) ------------------
  { f32x4 acc[4] = {}; GEMM_N_PF2(Wq_p, 0, acc); xpose_n(acc, bq[(w*3+0)*16+llo], lhi, llo, qfv[0], qscv[0]); FENCE; }
  { f32x4 acc[4] = {}; GEMM_N_PF2(Wq_p, 1, acc); xpose_n(acc, bq[(w*3+1)*16+llo], lhi, llo, qfv[1], qscv[1]); FENCE; }
  { f32x4 acc[4] = {}; GEMM_N_PF2(Wq_p, 2, acc); xpose_n(acc, bq[(w*3+2)*16+llo], lhi, llo, qfv[2], qscv[2]); FENCE; }

  // ---- K pass with INCREMENTAL gram -----------------------------------------
  {
    {
      f32x4 acc[4] = {}; GEMM_N_PF2(Wk_p, 0, acc);
      short8 kf[2]; xpose_n(acc, bk[(w*3+0)*16+llo], lhi, llo, kf, kscv[0]);
      __builtin_amdgcn_s_setprio(1);
      #pragma unroll
      for (int ks = 0; ks < 2; ++ks)
        #pragma unroll
        for (int mt = 0; mt < 3; ++mt)
          g[mt][0] = __builtin_amdgcn_mfma_f32_16x16x32_bf16(qfv[mt][ks], kf[ks], g[mt][0], 0, 0, 0);
      __builtin_amdgcn_s_setprio(0);
      FENCE;
    }
    {
      f32x4 acc[4] = {}; GEMM_N_PF2(Wk_p, 1, acc);
      short8 kf[2]; xpose_n(acc, bk[(w*3+1)*16+llo], lhi, llo, kf, kscv[1]);
      __builtin_amdgcn_s_setprio(1);
      #pragma unroll
      for (int ks = 0; ks < 2; ++ks)
        #pragma unroll
        for (int mt = 0; mt < 3; ++mt)
          g[mt][1] = __builtin_amdgcn_mfma_f32_16x16x32_bf16(qfv[mt][ks], kf[ks], g[mt][1], 0, 0, 0);
      __builtin_amdgcn_s_setprio(0);
      FENCE;
    }
    {
      f32x4 acc[4] = {}; GEMM_N_PF2(Wk_p, 2, acc);
      short8 kf[2]; xpose_n(acc, bk[(w*3+2)*16+llo], lhi, llo, kf, kscv[2]);
      __builtin_amdgcn_s_setprio(1);
      #pragma unroll
      for (int ks = 0; ks < 2; ++ks)
        #pragma unroll
        for (int mt = 0; mt < 3; ++mt)
          g[mt][2] = __builtin_amdgcn_mfma_f32_16x16x32_bf16(qfv[mt][ks], kf[ks], g[mt][2], 0, 0, 0);
      __builtin_amdgcn_s_setprio(0);
      FENCE;
    }
  }

  // gather invQ[c] for this lane's 12 output rows (c = mt*16 + lhi*4 + r)
  float invQv[3][4];
  #pragma unroll
  for (int mt = 0; mt < 3; ++mt)
    #pragma unroll
    for (int r = 0; r < 4; ++r)
      invQv[mt][r] = __shfl(qscv[mt], lhi * 4 + r, 64);

  __syncthreads();   // b2: all X reads done; region A reusable as E

  // ---- E store (normalized gram, 112B rows) + w1 fill -----------------------
  #pragma unroll
  for (int mt = 0; mt < 3; ++mt)
    #pragma unroll
    for (int dt = 0; dt < 3; ++dt)
      #pragma unroll
      for (int r = 0; r < 4; ++r) {
        int c = mt * 16 + lhi * 4 + r, d = dt * 16 + llo;
        float val = g[mt][dt][r] * invQv[mt][r] * kscv[dt];
        *(unsigned short*)(smem + REGA + (w * 48 + c) * ESTR + d * 2) = f2bf(val);
      }
  if (tid < 64)      *(float*)(smem + WOFF + tid * 4) = Wth1[tid] * SCALE_QK;
  else if (tid < 72) *(float*)(smem + WOFF + 256 + (tid - 64) * 4) = bth1[tid - 64];
  __syncthreads();   // b3

  // ---- talking-heads mix1, VECTORIZED: thread-per-(c, d-quad) ---------------
  for (int gi = tid; gi < 576; gi += 512) {
    int c = gi / 12, dq = (gi % 12) * 4;
    char* base = smem + REGA + c * ESTR + dq * 2;
    float in[8][4];
    #pragma unroll
    for (int hh = 0; hh < 8; ++hh) {
      short4v v = *(short4v*)(base + hh * (48 * ESTR));
      #pragma unroll
      for (int j = 0; j < 4; ++j) in[hh][j] = bf2f((unsigned short)v[j]);
    }
    #pragma unroll
    for (int gdx = 0; gdx < 8; ++gdx) {
      const float bsl = *(const float*)(smem + WOFF + 256 + gdx * 4);
      short4v o;
      #pragma unroll
      for (int j = 0; j < 4; ++j) {
        float t = bsl;
        #pragma unroll
        for (int hh = 0; hh < 8; ++hh)
          t += in[hh][j] * *(const float*)(smem + WOFF + (gdx * 8 + hh) * 4);
        o[j] = (short)f2bf(t);
      }
      *(short4v*)(base + gdx * (48 * ESTR)) = o;
    }
  }
  __syncthreads();   // b4

  // ---- row softmax over d (rows = (g,c), 384 of them; 112B stride) ----------
  // also overwrite the weight slot with w2/b2 (mix1 readers are past b4)
  if (tid < 64)      *(float*)(smem + WOFF + tid * 4) = Wth2[tid];
  else if (tid < 72) *(float*)(smem + WOFF + 256 + (tid - 64) * 4) = bth2[tid - 64];
  for (int row = tid; row < 384; row += 512) {
    char* rp = smem + REGA + row * ESTR;
    float vv[48];
    #pragma unroll
    for (int i = 0; i < 6; ++i) {
      short8 v8 = *(short8*)(rp + i * 16);
      #pragma unroll
      for (int j = 0; j < 8; ++j) vv[i * 8 + j] = bf2f((unsigned short)v8[j]);
    }
    float mx = vv[0];
    #pragma unroll
    for (int i = 1; i < 48; ++i) mx = fmaxf(mx, vv[i]);
    float sum = 0.f;
    #pragma unroll
    for (int i = 0; i < 48; ++i) { vv[i] = __expf(vv[i] - mx); sum += vv[i]; }
    float inv = 1.f / sum;
    #pragma unroll
    for (int i = 0; i < 6; ++i) {
      short8 o8;
      #pragma unroll
      for (int j = 0; j < 8; ++j) o8[j] = (short)f2bf(vv[i * 8 + j] * inv);
      *(short8*)(rp + i * 16) = o8;
    }
  }
  __syncthreads();   // b5

  // ---- talking-heads mix2, VECTORIZED (weights now w2/b2 in the slot) -------
  for (int gi = tid; gi < 576; gi += 512) {
    int c = gi / 12, dq = (gi % 12) * 4;
    char* base = smem + REGA + c * ESTR + dq * 2;
    float in[8][4];
    #pragma unroll
    for (int hh = 0; hh < 8; ++hh) {
      short4v v = *(short4v*)(base + hh * (48 * ESTR));
      #pragma unroll
      for (int j = 0; j < 4; ++j) in[hh][j] = bf2f((unsigned short)v[j]);
    }
    #pragma unroll
    for (int gdx = 0; gdx < 8; ++gdx) {
      const float bsl = *(const float*)(smem + WOFF + 256 + gdx * 4);
      short4v o;
      #pragma unroll
      for (int j = 0; j < 4; ++j) {
        float t = bsl;
        #pragma unroll
        for (int hh = 0; hh < 8; ++hh)
          t += in[hh][j] * *(const float*)(smem + WOFF + (gdx * 8 + hh) * 4);
        o[j] = (short)f2bf(t);
      }
      *(short4v*)(base + gdx * (48 * ESTR)) = o;
    }
  }
  __syncthreads();   // b6

  // ---- AV per head (head = w): A = E rows (112B stride), B = Vn -------------
  f32x4 oacc[3][4] = {};
  {
    #pragma unroll
    for (int ks = 0; ks < 2; ++ks) {
      short8 af[3];
      #pragma unroll
      for (int m = 0; m < 3; ++m) {
        short8 t = {0,0,0,0,0,0,0,0};
        if (!(ks == 1 && lhi >= 2))   // d >= 48 is K-pad
          t = *(const short8*)(smem + REGA + (w * 48 + m * 16 + llo) * ESTR + ks * 64 + lhi * 16);
        af[m] = t;
      }
      #pragma unroll
      for (int nt = 0; nt < 4; ++nt) {
        int n = nt * 16 + llo; int nc = (n > 48) ? 48 : n;   // pos clamp
        short8 bf8 = {0,0,0,0,0,0,0,0};
        if (!(ks == 1 && lhi >= 2))   // matching mask (unwritten Vn pads)
          bf8 = *(const short8*)(smem + REGB + nc * 784 + w * 96 + ks * 64 + lhi * 16);
        __builtin_amdgcn_s_setprio(1);
        #pragma unroll
        for (int m = 0; m < 3; ++m)
          oacc[m][nt] = __builtin_amdgcn_mfma_f32_16x16x32_bf16(af[m], bf8, oacc[m][nt], 0, 0, 0);
        __builtin_amdgcn_s_setprio(0);
      }
    }
  }
  __syncthreads();   // b7: all E reads done; region A reusable as O/relu buf

  // ---- O store (attn*V, pre-vlocal, pre-relu) -> region A [pos][ch] ---------
  #pragma unroll
  for (int m = 0; m < 3; ++m)
    #pragma unroll
    for (int nt = 0; nt < 4; ++nt) {
      const int n = nt * 16 + llo;
      if (n >= 49) continue;
      const int o0 = w * 48 + m * 16 + lhi * 4;
      short4v ot;
      #pragma unroll
      for (int r = 0; r < 4; ++r) ot[r] = (short)f2bf(oacc[m][nt][r]);
      *(short4v*)(smem + REGA + n * 784 + o0 * 2) = ot;
    }
  __syncthreads();   // b8

  // ---- depthwise 3x3 on Vn + bvl + O, ReLU -> region A in place -------------
  for (int idx = tid; idx < 2352; idx += 512) {
    int n = idx / 48, c8 = idx % 48;
    int o0 = c8 * 8;
    int y = n / 7, xq = n % 7;
    float a[8];
    #pragma unroll
    for (int j = 0; j < 8; ++j) a[j] = bvl[o0 + j];
    #pragma unroll
    for (int dy = 0; dy < 3; ++dy) {
      int yy = y + dy - 1;
      if (yy < 0 || yy > 6) continue;
      #pragma unroll
      for (int dx = 0; dx < 3; ++dx) {
        int xx = xq + dx - 1;
        if (xx < 0 || xx > 6) continue;
        short8 vv = *(const short8*)(smem + REGB + (yy * 7 + xx) * 784 + o0 * 2);
        const float* wp = Wvl + (dy * 3 + dx) * 384 + o0;
        #pragma unroll
        for (int j = 0; j < 8; ++j) a[j] += bf2f((unsigned short)vv[j]) * wp[j];
      }
    }
    char* p = smem + REGA + n * 784 + o0 * 2;
    short8 oc = *(short8*)p;
    short8 s8;
    #pragma unroll
    for (int j = 0; j < 8; ++j)
      s8[j] = (short)f2bf(fmaxf(bf2f((unsigned short)oc[j]) + a[j], 0.f));
    *(short8*)p = s8;
  }
  __syncthreads();   // b9

  // ---- P GEMM (3-wide x 2-deep B prefetch): out = relu @ Wp^T + bp ----------
  {
    f32x4 acc[4][3] = {};
    short8 b00 = *(const short8*)(Wp_p + (((w * 3 + 0) * 12 + 0) << 9) + (l << 3));
    short8 b01 = *(const short8*)(Wp_p + (((w * 3 + 1) * 12 + 0) << 9) + (l << 3));
    short8 b02 = *(const short8*)(Wp_p + (((w * 3 + 2) * 12 + 0) << 9) + (l << 3));
    short8 b10 = *(const short8*)(Wp_p + (((w * 3 + 0) * 12 + 1) << 9) + (l << 3));
    short8 b11 = *(const short8*)(Wp_p + (((w * 3 + 1) * 12 + 1) << 9) + (l << 3));
    short8 b12 = *(const short8*)(Wp_p + (((w * 3 + 2) * 12 + 1) << 9) + (l << 3));
    #pragma unroll
    for (int ks = 0; ks < 12; ++ks) {
      short8 bc0 = b00, bc1 = b01, bc2 = b02;
      b00 = b10; b01 = b11; b02 = b12;
      if (ks < 10) {
        b10 = *(const short8*)(Wp_p + (((w * 3 + 0) * 12 + ks + 2) << 9) + (l << 3));
        b11 = *(const short8*)(Wp_p + (((w * 3 + 1) * 12 + ks + 2) << 9) + (l << 3));
        b12 = *(const short8*)(Wp_p + (((w * 3 + 2) * 12 + ks + 2) << 9) + (l << 3));
      }
      short8 a[4];
      #pragma unroll
      for (int m = 0; m < 4; ++m) {
        int row = m * 16 + llo; row = (row > 48) ? 48 : row;
        a[m] = *(const short8*)(smem + REGA + row * 784 + ks * 64 + lhi * 16);
      }
      __builtin_amdgcn_s_setprio(1);
      #pragma unroll
      for (int m = 0; m < 4; ++m) {
        acc[m][0] = __builtin_amdgcn_mfma_f32_16x16x32_bf16(a[m], bc0, acc[m][0], 0, 0, 0);
        acc[m][1] = __builtin_amdgcn_mfma_f32_16x16x32_bf16(a[m], bc1, acc[m][1], 0, 0, 0);
        acc[m][2] = __builtin_amdgcn_mfma_f32_16x16x32_bf16(a[m], bc2, acc[m][2], 0, 0, 0);
      }
      __builtin_amdgcn_s_setprio(0);
    }
    float* ob = out + (size_t)b * (NPOS * DIMC);
    #pragma unroll
    for (int n = 0; n < 3; ++n) {
      const int o = (w * 3 + n) * 16 + llo;
      const float bias = bp[o];
      #pragma unroll
      for (int m = 0; m < 4; ++m)
        #pragma unroll
        for (int r = 0; r < 4; ++r) {
          int np = m * 16 + lhi * 4 + r;
          if (np < 49) ob[np * 384 + o] = acc[m][n][r] + bias;
        }
    }
  }
}

extern "C" void kernel_launch(void* const* d_in, const int* in_sizes, int n_in,
                              void* d_out, int out_size, void* d_ws, size_t ws_size,
                              hipStream_t stream) {
  const float* x    = (const float*)d_in[0];
  const float* Wq   = (const float*)d_in[1];
  const float* bq   = (const float*)d_in[2];
  const float* Wk   = (const float*)d_in[3];
  const float* bk   = (const float*)d_in[4];
  const float* Wv   = (const float*)d_in[5];
  const float* bv   = (const float*)d_in[6];
  const float* Wvl  = (const float*)d_in[7];
  const float* bvl  = (const float*)d_in[8];
  const float* Wth1 = (const float*)d_in[9];
  const float* bth1 = (const float*)d_in[10];
  const float* Wth2 = (const float*)d_in[11];
  const float* bth2 = (const float*)d_in[12];
  const float* Wp   = (const float*)d_in[13];
  const float* bp   = (const float*)d_in[14];
  unsigned short* Wbf = (unsigned short*)d_ws;   // 1.18 MB of scratch used
  float* out = (float*)d_out;

  hipLaunchKernelGGL(wconv_kernel, dim3(288), dim3(256), 0, stream,
                     Wq, Wk, Wv, Wp, Wbf);
  hipLaunchKernelGGL(attn_fused_kernel, dim3(2048), dim3(512), LDS_BYTES, stream,
                     x, bq, bk, bv, bp, Wvl, bvl, Wth1, bth1, Wth2, bth2, Wbf, out);
}

// Round 22
// 251.862 us; speedup vs baseline: 1.0119x; 1.0119x over previous
//
#include <hip/hip_runtime.h>
#include <hip/hip_bf16.h>

// ---------------------------------------------------------------------------
// Fused XCiT-style channel attention, one batch item per 512-thread block.
// B=2048, N=49 (7x7), DIM=384, HEADS=8, HD=48.
// FINAL (== R20, best measured 252.1us; R21's bias-epilogue variant
// regressed to 254.9 and is reverted).
// Structure: 76.8KB->81.7KB LDS, 2 blocks/CU; per-head wave ownership;
// 3-pass QKV (V store / Q xpose / K incremental gram, all 13-kstep with
// bias k-step and 2-deep B prefetch + setprio); padded-E middle with
// vectorized talking-heads mixes and strided softmax; AV + depthwise +
// P GEMM tail. Cumulative: 557 -> 252 us (2.21x).
// ---------------------------------------------------------------------------

typedef __attribute__((ext_vector_type(8))) short short8;   // 8 x bf16 (4 VGPR)
typedef __attribute__((ext_vector_type(4))) short short4v;  // 4 x bf16 (8B)
typedef __attribute__((ext_vector_type(4))) float f32x4;    // MFMA acc

#define NPOS   49
#define DIMC   384
#define SCALE_QK 0.14433756729740643f   // 48^-0.5

// LDS map (bytes):
//  REGA = 0     : X bf16 [49][392] (38416) -> E bf16 [8][48] rows of 112B
//                 (43008) -> O/relu bf16 [49][392] (38416)
//  WOFF = 43008 : 288B f32 weight slot (64 w + 8 b; w1 then w2 time-shared)
//  REGB = 43296 : Vn bf16 [49][392] ([pos][ch], stride 784B)
#define REGA 0
#define WOFF 43008
#define REGB 43296
#define ESTR 112              // padded E row stride (bytes)
#define LDS_BYTES 81712

// per-gemm permuted-W block: 24 nt * 13 ks * 512 lane-slots
#define WBLK 159744

__device__ __forceinline__ unsigned short f2bf(float f) {
  __hip_bfloat16 h = __float2bfloat16(f);
  unsigned short u;
  __builtin_memcpy(&u, &h, 2);
  return u;
}
__device__ __forceinline__ float bf2f(unsigned short u) {
  union { unsigned u; float f; } v; v.u = ((unsigned)u) << 16;
  return v.f;
}

// ---- prologue: permute Wq,Wk,Wv,Wp + biases into lane-ordered bf16 chunks
// (13 k-steps; ks=12 is the bias step: B[k=0][n]=bias[n], else 0).
__global__ void wconv_kernel(const float* __restrict__ Wq, const float* __restrict__ Wk,
                             const float* __restrict__ Wv, const float* __restrict__ Wp,
                             const float* __restrict__ bq, const float* __restrict__ bk,
                             const float* __restrict__ bv, const float* __restrict__ bp,
                             unsigned short* __restrict__ dst) {
  int t = blockIdx.x * 256 + threadIdx.x;
  if (t >= 79872) return;            // 4 gemms * 24 nt * 13 ks * 64 lanes
  int l = t & 63;
  int u = t >> 6;
  int ks = u % 13; u /= 13;
  int nt = u % 24;
  int g  = u / 24;
  const float* W  = (g == 0) ? Wq : (g == 1) ? Wk : (g == 2) ? Wv : Wp;
  const float* bb = (g == 0) ? bq : (g == 1) ? bk : (g == 2) ? bv : bp;
  int row = nt * 16 + (l & 15);
  short8 o8 = {0,0,0,0,0,0,0,0};
  if (ks < 12) {
    const float* sp = W + row * 384 + ks * 32 + (l >> 4) * 8;
    #pragma unroll
    for (int j = 0; j < 8; ++j) o8[j] = (short)f2bf(sp[j]);
  } else if ((l >> 4) == 0) {
    o8[0] = (short)f2bf(bb[row]);
  }
  *(short8*)(dst + (size_t)t * 8) = o8;
}

// 4-lane transpose of one RAW n-tile D-fragment into gram A/B fragments
// (pos = ks*32 + lhi*8 + j), plus per-channel inverse L2 norm (read-only acc).
__device__ __forceinline__ void xpose_n(const f32x4 (&acc)[4],
                                        int lhi, int llo,
                                        short8 (&fr)[2], float& sc) {
  float ss = 0.f;
  #pragma unroll
  for (int m = 0; m < 4; ++m)
    #pragma unroll
    for (int r = 0; r < 4; ++r) {
      int np = m * 16 + lhi * 4 + r;
      float v = acc[m][r];
      if (np < 49) ss += v * v;
    }
  ss += __shfl_xor(ss, 16, 64);
  ss += __shfl_xor(ss, 32, 64);
  sc = 1.f / fmaxf(sqrtf(ss), 1e-12f);
  const int src_lo = llo + ((lhi & 1) << 5);
  const int src_hi = src_lo + 16;
  #pragma unroll
  for (int m = 0; m < 4; ++m) {
    unsigned p0 = (unsigned)f2bf(acc[m][0]) | ((unsigned)f2bf(acc[m][1]) << 16);
    unsigned p1 = (unsigned)f2bf(acc[m][2]) | ((unsigned)f2bf(acc[m][3]) << 16);
    int lo0 = __shfl((int)p0, src_lo, 64);
    int lo1 = __shfl((int)p1, src_lo, 64);
    int hi0 = __shfl((int)p0, src_hi, 64);
    int hi1 = __shfl((int)p1, src_hi, 64);
    if ((lhi >> 1) == (m & 1)) {
      union { int i[4]; short8 s; } u;
      u.i[0] = lo0; u.i[1] = lo1; u.i[2] = hi0; u.i[3] = hi1;
      fr[m >> 1] = u.s;
    }
  }
  // zero pos>=49 in the ks=1 fragment (lhi==2: keep pos48; lhi==3: all pad)
  if (lhi == 2) {
    union { int i[4]; short8 s; } u; u.s = fr[1];
    u.i[0] &= 0xFFFF; u.i[1] = 0; u.i[2] = 0; u.i[3] = 0;
    fr[1] = u.s;
  } else if (lhi == 3) {
    short8 z = {0,0,0,0,0,0,0,0};
    fr[1] = z;
  }
}

// ---- main fused kernel -----------------------------------------------------
__global__ __launch_bounds__(512, 4) void attn_fused_kernel(
    const float* __restrict__ x,
    const float* __restrict__ Wvl, const float* __restrict__ bvl,
    const float* __restrict__ Wth1, const float* __restrict__ bth1,
    const float* __restrict__ Wth2, const float* __restrict__ bth2,
    const unsigned short* __restrict__ Wbf,
    float* __restrict__ out) {
  extern __shared__ char smem[];
  const int tid = threadIdx.x;
  const int l   = tid & 63;
  const int w   = tid >> 6;          // wave 0..7 == head h
  const int lhi = l >> 4;            // 0..3
  const int llo = l & 15;
  const int b   = blockIdx.x;

  const float* xb = x + (size_t)b * (NPOS * DIMC);
  const unsigned short* Wq_p = Wbf;
  const unsigned short* Wk_p = Wbf + WBLK;
  const unsigned short* Wv_p = Wbf + 2 * WBLK;
  const unsigned short* Wp_p = Wbf + 3 * WBLK;

  // ---- phase 0: stage x_b -> X bf16 [49][392]; ones-column at col 384 -------
  for (int idx = tid; idx < 49 * 48; idx += 512) {
    int row = idx / 48, c8 = idx % 48;
    const float4 v0 = *(const float4*)(xb + row * 384 + c8 * 8);
    const float4 v1 = *(const float4*)(xb + row * 384 + c8 * 8 + 4);
    short8 s;
    s[0] = (short)f2bf(v0.x); s[1] = (short)f2bf(v0.y);
    s[2] = (short)f2bf(v0.z); s[3] = (short)f2bf(v0.w);
    s[4] = (short)f2bf(v1.x); s[5] = (short)f2bf(v1.y);
    s[6] = (short)f2bf(v1.z); s[7] = (short)f2bf(v1.w);
    *(short8*)(smem + REGA + row * 784 + c8 * 16) = s;
  }
  if (tid < 49) {                    // cols 384..391 = {1, 0 x7}
    short8 u1 = {0,0,0,0,0,0,0,0};
    u1[0] = (short)f2bf(1.0f);
    *(short8*)(smem + REGA + tid * 784 + 768) = u1;
  }
  if (tid >= 64 && tid < 68) {       // zero REGA[38416..38480): ks=12 row-48
    short8 z = {0,0,0,0,0,0,0,0};    // A-read overruns X into here; W=0 there
    *(short8*)(smem + REGA + 38416 + (tid - 64) * 16) = z;   // but NaN*0=NaN.
  }
  __syncthreads();   // b1

  short8 qfv[3][2];
  float  qscv[3], kscv[3];
  f32x4 g[3][3] = {};                // gram acc, filled during the K pass

#define FENCE asm volatile("" ::: "memory")
  // 2-deep B-prefetch GEMM body; MFMA cluster wrapped in setprio (T5).
#define GEMM_N_PF2(WPTR, NIDX, ACC)                                            \
  {                                                                            \
    short8 bp0 = *(const short8*)(WPTR + (((w * 3 + NIDX) * 13 + 0) << 9) + (l << 3)); \
    short8 bp1 = *(const short8*)(WPTR + (((w * 3 + NIDX) * 13 + 1) << 9) + (l << 3)); \
    _Pragma("unroll")                                                          \
    for (int ks = 0; ks < 13; ++ks) {                                          \
      short8 bc = bp0; bp0 = bp1;                                              \
      if (ks < 11)                                                             \
        bp1 = *(const short8*)(WPTR + (((w * 3 + NIDX) * 13 + ks + 2) << 9) + (l << 3)); \
      short8 a[4];                                                             \
      _Pragma("unroll")                                                        \
      for (int m = 0; m < 4; ++m) {                                            \
        int row = m * 16 + llo; row = (row > 48) ? 48 : row;                   \
        a[m] = *(const short8*)(smem + REGA + row * 784 + ks * 64 + lhi * 16); \
      }                                                                        \
      __builtin_amdgcn_s_setprio(1);                                           \
      _Pragma("unroll")                                                        \
      for (int m = 0; m < 4; ++m)                                              \
        ACC[m] = __builtin_amdgcn_mfma_f32_16x16x32_bf16(a[m], bc, ACC[m], 0, 0, 0); \
      __builtin_amdgcn_s_setprio(0);                                           \
    }                                                                          \
  }

  // ---- V pass (per n-tile, 2-deep B-prefetch; biased V -> REGB [pos][ch]) ---
  #pragma unroll
  for (int n = 0; n < 3; ++n) {
    f32x4 aV[4] = {};
    GEMM_N_PF2(Wv_p, n, aV);
    const int o = (w * 3 + n) * 16 + llo;
    #pragma unroll
    for (int m = 0; m < 4; ++m)
      #pragma unroll
      for (int r = 0; r < 4; ++r) {
        int np = m * 16 + lhi * 4 + r;
        if (np < 49)
          *(unsigned short*)(smem + REGB + np * 784 + o * 2) = f2bf(aV[m][r]);
      }
    FENCE;
  }

  // ---- Q pass (2-deep B-prefetch) -> raw qf + inv norms ---------------------
  { f32x4 acc[4] = {}; GEMM_N_PF2(Wq_p, 0, acc); xpose_n(acc, lhi, llo, qfv[0], qscv[0]); FENCE; }
  { f32x4 acc[4] = {}; GEMM_N_PF2(Wq_p, 1, acc); xpose_n(acc, lhi, llo, qfv[1], qscv[1]); FENCE; }
  { f32x4 acc[4] = {}; GEMM_N_PF2(Wq_p, 2, acc); xpose_n(acc, lhi, llo, qfv[2], qscv[2]); FENCE; }

  // ---- K pass (2-deep B-prefetch) with INCREMENTAL gram ---------------------
  {
    {
      f32x4 acc[4] = {}; GEMM_N_PF2(Wk_p, 0, acc);
      short8 kf[2]; xpose_n(acc, lhi, llo, kf, kscv[0]);
      __builtin_amdgcn_s_setprio(1);
      #pragma unroll
      for (int ks = 0; ks < 2; ++ks)
        #pragma unroll
        for (int mt = 0; mt < 3; ++mt)
          g[mt][0] = __builtin_amdgcn_mfma_f32_16x16x32_bf16(qfv[mt][ks], kf[ks], g[mt][0], 0, 0, 0);
      __builtin_amdgcn_s_setprio(0);
      FENCE;
    }
    {
      f32x4 acc[4] = {}; GEMM_N_PF2(Wk_p, 1, acc);
      short8 kf[2]; xpose_n(acc, lhi, llo, kf, kscv[1]);
      __builtin_amdgcn_s_setprio(1);
      #pragma unroll
      for (int ks = 0; ks < 2; ++ks)
        #pragma unroll
        for (int mt = 0; mt < 3; ++mt)
          g[mt][1] = __builtin_amdgcn_mfma_f32_16x16x32_bf16(qfv[mt][ks], kf[ks], g[mt][1], 0, 0, 0);
      __builtin_amdgcn_s_setprio(0);
      FENCE;
    }
    {
      f32x4 acc[4] = {}; GEMM_N_PF2(Wk_p, 2, acc);
      short8 kf[2]; xpose_n(acc, lhi, llo, kf, kscv[2]);
      __builtin_amdgcn_s_setprio(1);
      #pragma unroll
      for (int ks = 0; ks < 2; ++ks)
        #pragma unroll
        for (int mt = 0; mt < 3; ++mt)
          g[mt][2] = __builtin_amdgcn_mfma_f32_16x16x32_bf16(qfv[mt][ks], kf[ks], g[mt][2], 0, 0, 0);
      __builtin_amdgcn_s_setprio(0);
      FENCE;
    }
  }

  // gather invQ[c] for this lane's 12 output rows (c = mt*16 + lhi*4 + r)
  float invQv[3][4];
  #pragma unroll
  for (int mt = 0; mt < 3; ++mt)
    #pragma unroll
    for (int r = 0; r < 4; ++r)
      invQv[mt][r] = __shfl(qscv[mt], lhi * 4 + r, 64);

  __syncthreads();   // b2: all X reads done; region A reusable as E

  // ---- E store (normalized gram, 112B rows) + w1 fill -----------------------
  #pragma unroll
  for (int mt = 0; mt < 3; ++mt)
    #pragma unroll
    for (int dt = 0; dt < 3; ++dt)
      #pragma unroll
      for (int r = 0; r < 4; ++r) {
        int c = mt * 16 + lhi * 4 + r, d = dt * 16 + llo;
        float val = g[mt][dt][r] * invQv[mt][r] * kscv[dt];
        *(unsigned short*)(smem + REGA + (w * 48 + c) * ESTR + d * 2) = f2bf(val);
      }
  if (tid < 64)      *(float*)(smem + WOFF + tid * 4) = Wth1[tid] * SCALE_QK;
  else if (tid < 72) *(float*)(smem + WOFF + 256 + (tid - 64) * 4) = bth1[tid - 64];
  __syncthreads();   // b3

  // ---- talking-heads mix1, VECTORIZED: thread-per-(c, d-quad) ---------------
  for (int gi = tid; gi < 576; gi += 512) {
    int c = gi / 12, dq = (gi % 12) * 4;
    char* base = smem + REGA + c * ESTR + dq * 2;
    float in[8][4];
    #pragma unroll
    for (int hh = 0; hh < 8; ++hh) {
      short4v v = *(short4v*)(base + hh * (48 * ESTR));
      #pragma unroll
      for (int j = 0; j < 4; ++j) in[hh][j] = bf2f((unsigned short)v[j]);
    }
    #pragma unroll
    for (int gdx = 0; gdx < 8; ++gdx) {
      const float bsl = *(const float*)(smem + WOFF + 256 + gdx * 4);
      short4v o;
      #pragma unroll
      for (int j = 0; j < 4; ++j) {
        float t = bsl;
        #pragma unroll
        for (int hh = 0; hh < 8; ++hh)
          t += in[hh][j] * *(const float*)(smem + WOFF + (gdx * 8 + hh) * 4);
        o[j] = (short)f2bf(t);
      }
      *(short4v*)(base + gdx * (48 * ESTR)) = o;
    }
  }
  __syncthreads();   // b4

  // ---- row softmax over d (rows = (g,c), 384 of them; 112B stride) ----------
  // also overwrite the weight slot with w2/b2 (mix1 readers are past b4)
  if (tid < 64)      *(float*)(smem + WOFF + tid * 4) = Wth2[tid];
  else if (tid < 72) *(float*)(smem + WOFF + 256 + (tid - 64) * 4) = bth2[tid - 64];
  for (int row = tid; row < 384; row += 512) {
    char* rp = smem + REGA + row * ESTR;
    float vv[48];
    #pragma unroll
    for (int i = 0; i < 6; ++i) {
      short8 v8 = *(short8*)(rp + i * 16);
      #pragma unroll
      for (int j = 0; j < 8; ++j) vv[i * 8 + j] = bf2f((unsigned short)v8[j]);
    }
    float mx = vv[0];
    #pragma unroll
    for (int i = 1; i < 48; ++i) mx = fmaxf(mx, vv[i]);
    float sum = 0.f;
    #pragma unroll
    for (int i = 0; i < 48; ++i) { vv[i] = __expf(vv[i] - mx); sum += vv[i]; }
    float inv = 1.f / sum;
    #pragma unroll
    for (int i = 0; i < 6; ++i) {
      short8 o8;
      #pragma unroll
      for (int j = 0; j < 8; ++j) o8[j] = (short)f2bf(vv[i * 8 + j] * inv);
      *(short8*)(rp + i * 16) = o8;
    }
  }
  __syncthreads();   // b5

  // ---- talking-heads mix2, VECTORIZED (weights now w2/b2 in the slot) -------
  for (int gi = tid; gi < 576; gi += 512) {
    int c = gi / 12, dq = (gi % 12) * 4;
    char* base = smem + REGA + c * ESTR + dq * 2;
    float in[8][4];
    #pragma unroll
    for (int hh = 0; hh < 8; ++hh) {
      short4v v = *(short4v*)(base + hh * (48 * ESTR));
      #pragma unroll
      for (int j = 0; j < 4; ++j) in[hh][j] = bf2f((unsigned short)v[j]);
    }
    #pragma unroll
    for (int gdx = 0; gdx < 8; ++gdx) {
      const float bsl = *(const float*)(smem + WOFF + 256 + gdx * 4);
      short4v o;
      #pragma unroll
      for (int j = 0; j < 4; ++j) {
        float t = bsl;
        #pragma unroll
        for (int hh = 0; hh < 8; ++hh)
          t += in[hh][j] * *(const float*)(smem + WOFF + (gdx * 8 + hh) * 4);
        o[j] = (short)f2bf(t);
      }
      *(short4v*)(base + gdx * (48 * ESTR)) = o;
    }
  }
  __syncthreads();   // b6

  // ---- AV per head (head = w): A = E rows (112B stride), B = Vn -------------
  f32x4 oacc[3][4] = {};
  {
    #pragma unroll
    for (int ks = 0; ks < 2; ++ks) {
      short8 af[3];
      #pragma unroll
      for (int m = 0; m < 3; ++m) {
        short8 t = {0,0,0,0,0,0,0,0};
        if (!(ks == 1 && lhi >= 2))   // d >= 48 is K-pad
          t = *(const short8*)(smem + REGA + (w * 48 + m * 16 + llo) * ESTR + ks * 64 + lhi * 16);
        af[m] = t;
      }
      #pragma unroll
      for (int nt = 0; nt < 4; ++nt) {
        int n = nt * 16 + llo; int nc = (n > 48) ? 48 : n;   // pos clamp
        short8 bf8 = {0,0,0,0,0,0,0,0};
        if (!(ks == 1 && lhi >= 2))   // matching mask (unwritten Vn pads)
          bf8 = *(const short8*)(smem + REGB + nc * 784 + w * 96 + ks * 64 + lhi * 16);
        __builtin_amdgcn_s_setprio(1);
        #pragma unroll
        for (int m = 0; m < 3; ++m)
          oacc[m][nt] = __builtin_amdgcn_mfma_f32_16x16x32_bf16(af[m], bf8, oacc[m][nt], 0, 0, 0);
        __builtin_amdgcn_s_setprio(0);
      }
    }
  }
  __syncthreads();   // b7: all E reads done; region A reusable as O/relu buf

  // ---- O store (attn*V, pre-vlocal, pre-relu) -> region A [pos][ch] ---------
  #pragma unroll
  for (int m = 0; m < 3; ++m)
    #pragma unroll
    for (int nt = 0; nt < 4; ++nt) {
      const int n = nt * 16 + llo;
      if (n >= 49) continue;
      const int o0 = w * 48 + m * 16 + lhi * 4;
      short4v ot;
      #pragma unroll
      for (int r = 0; r < 4; ++r) ot[r] = (short)f2bf(oacc[m][nt][r]);
      *(short4v*)(smem + REGA + n * 784 + o0 * 2) = ot;
    }
  __syncthreads();   // b8

  // ---- depthwise 3x3 on Vn + bvl + O, ReLU -> region A; restore ones-col ----
  for (int idx = tid; idx < 2352; idx += 512) {
    int n = idx / 48, c8 = idx % 48;
    int o0 = c8 * 8;
    int y = n / 7, xq = n % 7;
    float a[8];
    #pragma unroll
    for (int j = 0; j < 8; ++j) a[j] = bvl[o0 + j];
    #pragma unroll
    for (int dy = 0; dy < 3; ++dy) {
      int yy = y + dy - 1;
      if (yy < 0 || yy > 6) continue;
      #pragma unroll
      for (int dx = 0; dx < 3; ++dx) {
        int xx = xq + dx - 1;
        if (xx < 0 || xx > 6) continue;
        short8 vv = *(const short8*)(smem + REGB + (yy * 7 + xx) * 784 + o0 * 2);
        const float* wp = Wvl + (dy * 3 + dx) * 384 + o0;
        #pragma unroll
        for (int j = 0; j < 8; ++j) a[j] += bf2f((unsigned short)vv[j]) * wp[j];
      }
    }
    char* p = smem + REGA + n * 784 + o0 * 2;
    short8 oc = *(short8*)p;
    short8 s8;
    #pragma unroll
    for (int j = 0; j < 8; ++j)
      s8[j] = (short)f2bf(fmaxf(bf2f((unsigned short)oc[j]) + a[j], 0.f));
    *(short8*)p = s8;
  }
  if (tid < 49) {                    // restore ones-column for P GEMM bias step
    short8 u1 = {0,0,0,0,0,0,0,0};
    u1[0] = (short)f2bf(1.0f);
    *(short8*)(smem + REGA + tid * 784 + 768) = u1;
  }
  if (tid >= 64 && tid < 68) {       // re-zero the ks=12 row-48 overrun window
    short8 z = {0,0,0,0,0,0,0,0};
    *(short8*)(smem + REGA + 38416 + (tid - 64) * 16) = z;
  }
  __syncthreads();   // b9

  // ---- P GEMM (3-wide x 2-deep B prefetch): out = relu @ Wp^T (+bp) ---------
  {
    f32x4 acc[4][3] = {};
    short8 b00 = *(const short8*)(Wp_p + (((w * 3 + 0) * 13 + 0) << 9) + (l << 3));
    short8 b01 = *(const short8*)(Wp_p + (((w * 3 + 1) * 13 + 0) << 9) + (l << 3));
    short8 b02 = *(const short8*)(Wp_p + (((w * 3 + 2) * 13 + 0) << 9) + (l << 3));
    short8 b10 = *(const short8*)(Wp_p + (((w * 3 + 0) * 13 + 1) << 9) + (l << 3));
    short8 b11 = *(const short8*)(Wp_p + (((w * 3 + 1) * 13 + 1) << 9) + (l << 3));
    short8 b12 = *(const short8*)(Wp_p + (((w * 3 + 2) * 13 + 1) << 9) + (l << 3));
    #pragma unroll
    for (int ks = 0; ks < 13; ++ks) {
      short8 bc0 = b00, bc1 = b01, bc2 = b02;
      b00 = b10; b01 = b11; b02 = b12;
      if (ks < 11) {
        b10 = *(const short8*)(Wp_p + (((w * 3 + 0) * 13 + ks + 2) << 9) + (l << 3));
        b11 = *(const short8*)(Wp_p + (((w * 3 + 1) * 13 + ks + 2) << 9) + (l << 3));
        b12 = *(const short8*)(Wp_p + (((w * 3 + 2) * 13 + ks + 2) << 9) + (l << 3));
      }
      short8 a[4];
      #pragma unroll
      for (int m = 0; m < 4; ++m) {
        int row = m * 16 + llo; row = (row > 48) ? 48 : row;
        a[m] = *(const short8*)(smem + REGA + row * 784 + ks * 64 + lhi * 16);
      }
      __builtin_amdgcn_s_setprio(1);
      #pragma unroll
      for (int m = 0; m < 4; ++m) {
        acc[m][0] = __builtin_amdgcn_mfma_f32_16x16x32_bf16(a[m], bc0, acc[m][0], 0, 0, 0);
        acc[m][1] = __builtin_amdgcn_mfma_f32_16x16x32_bf16(a[m], bc1, acc[m][1], 0, 0, 0);
        acc[m][2] = __builtin_amdgcn_mfma_f32_16x16x32_bf16(a[m], bc2, acc[m][2], 0, 0, 0);
      }
      __builtin_amdgcn_s_setprio(0);
    }
    float* ob = out + (size_t)b * (NPOS * DIMC);
    #pragma unroll
    for (int n = 0; n < 3; ++n) {
      const int o = (w * 3 + n) * 16 + llo;
      #pragma unroll
      for (int m = 0; m < 4; ++m)
        #pragma unroll
        for (int r = 0; r < 4; ++r) {
          int np = m * 16 + lhi * 4 + r;
          if (np < 49) ob[np * 384 + o] = acc[m][n][r];
        }
    }
  }
}

extern "C" void kernel_launch(void* const* d_in, const int* in_sizes, int n_in,
                              void* d_out, int out_size, void* d_ws, size_t ws_size,
                              hipStream_t stream) {
  const float* x    = (const float*)d_in[0];
  const float* Wq   = (const float*)d_in[1];
  const float* bq   = (const float*)d_in[2];
  const float* Wk   = (const float*)d_in[3];
  const float* bk   = (const float*)d_in[4];
  const float* Wv   = (const float*)d_in[5];
  const float* bv   = (const float*)d_in[6];
  const float* Wvl  = (const float*)d_in[7];
  const float* bvl  = (const float*)d_in[8];
  const float* Wth1 = (const float*)d_in[9];
  const float* bth1 = (const float*)d_in[10];
  const float* Wth2 = (const float*)d_in[11];
  const float* bth2 = (const float*)d_in[12];
  const float* Wp   = (const float*)d_in[13];
  const float* bp   = (const float*)d_in[14];
  unsigned short* Wbf = (unsigned short*)d_ws;   // 1.25 MB of scratch used
  float* out = (float*)d_out;

  hipLaunchKernelGGL(wconv_kernel, dim3(312), dim3(256), 0, stream,
                     Wq, Wk, Wv, Wp, bq, bk, bv, bp, Wbf);
  hipLaunchKernelGGL(attn_fused_kernel, dim3(2048), dim3(512), LDS_BYTES, stream,
                     x, Wvl, bvl, Wth1, bth1, Wth2, bth2, Wbf, out);
}